// Round 8
// baseline (659.793 us; speedup 1.0000x reference)
//
#include <hip/hip_runtime.h>
#include <math.h>

// Shapes (fixed by the problem)
#define BB 16
#define C  512
#define P  4
#define NN 1024
#define BP (BB*P)     // 64
#define PN (P*NN)     // 4096 floats: stride between channels c for fixed (b,p)

typedef short bf16x8 __attribute__((ext_vector_type(8)));
typedef float f32x4  __attribute__((ext_vector_type(4)));
typedef unsigned short ushort_t;

#define XTFH 2048                    // shorts per (buf,dtype): 4*64*8
#define TILE_SH 32768                // shorts per act tile (16kt*4n*64l*8j)
#define NTILES 1024                  // 16 nt * 64 bp

__device__ __forceinline__ ushort_t bf16rne(float f) {
    unsigned u = __float_as_uint(f);
    u += 0x7FFFu + ((u >> 16) & 1u);
    return (ushort_t)(u >> 16);
}
__device__ __forceinline__ float bf16tof(ushort_t h) {
    return __uint_as_float(((unsigned)h) << 16);
}

// ---------------------------------------------------------------------------
// Kernel 0: split weights into bf16 hi/lo.  512 blocks x 256.
// ---------------------------------------------------------------------------
__global__ __launch_bounds__(256) void k_split(const float* __restrict__ w_qkv,
                                               const float* __restrict__ w_out,
                                               ushort_t* __restrict__ wv_hi,
                                               ushort_t* __restrict__ wv_lo,
                                               ushort_t* __restrict__ wo_hi,
                                               ushort_t* __restrict__ wo_lo) {
    const int i = blockIdx.x * 256 + threadIdx.x;   // 0..131071
    const int e = i * 4;
    const float* src; ushort_t *dh, *dl; int off;
    if (e < C * C) { src = w_qkv + (size_t)(1 + C) * C; dh = wv_hi; dl = wv_lo; off = e; }
    else           { src = w_out;                       dh = wo_hi; dl = wo_lo; off = e - C * C; }
    const float4 v = *reinterpret_cast<const float4*>(src + off);
    const float vv[4] = {v.x, v.y, v.z, v.w};
    ushort_t h[4], l[4];
    #pragma unroll
    for (int j = 0; j < 4; ++j) {
        h[j] = bf16rne(vv[j]);
        l[j] = bf16rne(vv[j] - bf16tof(h[j]));
    }
    uint2 ph, pl;
    ph.x = (unsigned)h[0] | ((unsigned)h[1] << 16);
    ph.y = (unsigned)h[2] | ((unsigned)h[3] << 16);
    pl.x = (unsigned)l[0] | ((unsigned)l[1] << 16);
    pl.y = (unsigned)l[2] | ((unsigned)l[3] << 16);
    *reinterpret_cast<uint2*>(dh + off) = ph;
    *reinterpret_cast<uint2*>(dl + off) = pl;
}

// ---------------------------------------------------------------------------
// Kernel 1: qpart[cc][bp][n] = sum_{c in chunk cc} w_q[c] * x[b,c,p,n]
// ---------------------------------------------------------------------------
__global__ __launch_bounds__(256) void k_query(const float* __restrict__ x,
                                               const float* __restrict__ w_qkv,
                                               float4* __restrict__ qpart4) {
    __shared__ float wq[64];
    const int bp = blockIdx.x >> 3, cc = blockIdx.x & 7;
    const int b = bp >> 2, p = bp & 3;
    const int tid = threadIdx.x;
    if (tid < 64) wq[tid] = w_qkv[cc * 64 + tid];
    __syncthreads();
    const float* xb = x + (size_t)b * C * PN + (size_t)p * NN;
    f32x4 acc[8];
    #pragma unroll
    for (int a = 0; a < 8; ++a) acc[a] = (f32x4){0.f, 0.f, 0.f, 0.f};
    #pragma unroll 8
    for (int i = 0; i < 64; ++i) {
        const float4 v = *reinterpret_cast<const float4*>(xb + (size_t)(cc * 64 + i) * PN + tid * 4);
        const float wv = wq[i];
        acc[i & 7][0] = fmaf(v.x, wv, acc[i & 7][0]);
        acc[i & 7][1] = fmaf(v.y, wv, acc[i & 7][1]);
        acc[i & 7][2] = fmaf(v.z, wv, acc[i & 7][2]);
        acc[i & 7][3] = fmaf(v.w, wv, acc[i & 7][3]);
    }
    f32x4 s = ((acc[0] + acc[1]) + (acc[2] + acc[3])) + ((acc[4] + acc[5]) + (acc[6] + acc[7]));
    float4 o; o.x = s[0]; o.y = s[1]; o.z = s[2]; o.w = s[3];
    qpart4[(cc * BP + bp) * 256 + tid] = o;
}

// ---------------------------------------------------------------------------
// Kernel 2: scores = softmax(sum_cc qpart) over N, per bp.  grid BP blocks.
// ---------------------------------------------------------------------------
__global__ __launch_bounds__(256) void k_softmax(const float4* __restrict__ qpart4,
                                                 float4* __restrict__ scores4) {
    __shared__ float red[256];
    const int bp = blockIdx.x, tid = threadIdx.x;
    float v[4] = {0.f, 0.f, 0.f, 0.f};
    #pragma unroll
    for (int cc = 0; cc < 8; ++cc) {
        const float4 q = qpart4[(cc * BP + bp) * 256 + tid];
        v[0] += q.x; v[1] += q.y; v[2] += q.z; v[3] += q.w;
    }
    float m = fmaxf(fmaxf(v[0], v[1]), fmaxf(v[2], v[3]));
    red[tid] = m; __syncthreads();
    for (int s = 128; s > 0; s >>= 1) {
        if (tid < s) red[tid] = fmaxf(red[tid], red[tid + s]);
        __syncthreads();
    }
    m = red[0]; __syncthreads();
    float sum = 0.f;
    #pragma unroll
    for (int j = 0; j < 4; ++j) { v[j] = expf(v[j] - m); sum += v[j]; }
    red[tid] = sum; __syncthreads();
    for (int s = 128; s > 0; s >>= 1) {
        if (tid < s) red[tid] += red[tid + s];
        __syncthreads();
    }
    const float inv = 1.0f / red[0];
    float4 o; o.x = v[0] * inv; o.y = v[1] * inv; o.z = v[2] * inv; o.w = v[3] * inv;
    scores4[bp * 256 + tid] = o;
}

// ---------------------------------------------------------------------------
// Kernel 3: xs[bp][c] = sum_n x[b,c,p,n] * scores[bp][n]
// ---------------------------------------------------------------------------
__global__ __launch_bounds__(256) void k_xs(const float* __restrict__ x,
                                            const float4* __restrict__ scores4,
                                            float* __restrict__ xs) {
    __shared__ float4 sc4[256];
    const int bp = blockIdx.x >> 4, cc = blockIdx.x & 15;
    const int b = bp >> 2, p = bp & 3;
    const int tid = threadIdx.x;
    sc4[tid] = scores4[bp * 256 + tid];
    __syncthreads();
    const int wave = tid >> 6, lane = tid & 63;
    const float* xb = x + (size_t)b * C * PN + (size_t)p * NN;
    #pragma unroll
    for (int r = 0; r < 8; ++r) {
        const int c = cc * 32 + wave * 8 + r;
        const float4* row4 = reinterpret_cast<const float4*>(xb + (size_t)c * PN);
        float a0 = 0.f, a1 = 0.f, a2 = 0.f, a3 = 0.f;
        #pragma unroll
        for (int j = 0; j < 4; ++j) {
            const float4 xv = row4[lane + 64 * j];
            const float4 sv = sc4[lane + 64 * j];
            a0 = fmaf(xv.x, sv.x, a0);
            a1 = fmaf(xv.y, sv.y, a1);
            a2 = fmaf(xv.z, sv.z, a2);
            a3 = fmaf(xv.w, sv.w, a3);
        }
        float acc = (a0 + a1) + (a2 + a3);
        #pragma unroll
        for (int off = 32; off > 0; off >>= 1) acc += __shfl_down(acc, off);
        if (lane == 0) xs[bp * C + c] = acc;
    }
}

// ---------------------------------------------------------------------------
// Kernel 4: cv[bp][o] = b_qkv[1+o] + sum_c w_key[o][c] * xs[bp][c]
// ---------------------------------------------------------------------------
__global__ __launch_bounds__(256) void k_cv(const float* __restrict__ xs,
                                            const float* __restrict__ w_qkv,
                                            const float* __restrict__ b_qkv,
                                            float* __restrict__ cv) {
    __shared__ float xsl[C];
    const int bp = blockIdx.x, tid = threadIdx.x;
    for (int i = tid; i < C; i += 256) xsl[i] = xs[bp * C + i];
    __syncthreads();
    const int wave = tid >> 6, lane = tid & 63;
    for (int o = wave; o < C; o += 4) {
        const float* wr = w_qkv + (size_t)(1 + o) * C;
        float acc = 0.f;
        #pragma unroll
        for (int j = 0; j < 8; ++j) acc = fmaf(wr[lane + 64 * j], xsl[lane + 64 * j], acc);
        #pragma unroll
        for (int off = 32; off > 0; off >>= 1) acc += __shfl_down(acc, off);
        if (lane == 0) cv[bp * C + o] = acc + b_qkv[1 + o];
    }
}

// ---------------------------------------------------------------------------
// Kernel 5a (split path): k_value — act = split(relu(Wv@x + b_v) * cv),
// written FRAG-LINEAR to global ws. LDS = xtf 16 KB only -> ~3 blocks/CU.
// MFMA maps (16x16x32, m89-verified): A[row=l&15][k=(l>>4)*8+j],
//   B[k=(l>>4)*8+j][col=l&15], D[col=l&15][row=(l>>4)*4+reg].
// ---------------------------------------------------------------------------
__global__ __launch_bounds__(512) void k_value(
    const float* __restrict__ x,
    const ushort_t* __restrict__ wv_hi, const ushort_t* __restrict__ wv_lo,
    const float* __restrict__ b_qkv, const float* __restrict__ cv,
    ushort_t* __restrict__ act_hi, ushort_t* __restrict__ act_lo) {

    __shared__ ushort_t xtf[2 * 2 * XTFH];           // [buf][dtype][XTFH]

    const int nt = blockIdx.x, bp = blockIdx.y;
    const int b = bp >> 2, p = bp & 3;
    const int n0 = nt * 64;
    const int tid = threadIdx.x;
    const int w  = tid >> 6;
    const int l  = tid & 63;
    const int lr = l & 15;
    const int lg = l >> 4;

    const float* xb = x + (size_t)b * C * PN + (size_t)p * NN + n0;
    const size_t tb = (size_t)(bp * 16 + nt) * TILE_SH;

    const int g_col = tid & 63;
    const int g_k4  = (tid >> 6) * 4;
    const int st_off = (((g_col >> 4) * 64 + (g_k4 >> 3) * 16 + (g_col & 15)) * 8) + (g_k4 & 7);

    f32x4 acc[4][4];
    #pragma unroll
    for (int m = 0; m < 4; ++m)
        #pragma unroll
        for (int n = 0; n < 4; ++n) acc[m][n] = (f32x4){0.f, 0.f, 0.f, 0.f};

    // prologue: stage kt=0 into buffer 0
    {
        float xg[4];
        #pragma unroll
        for (int jj = 0; jj < 4; ++jj) xg[jj] = xb[(size_t)(g_k4 + jj) * PN + g_col];
        ushort_t h[4], lo[4];
        #pragma unroll
        for (int jj = 0; jj < 4; ++jj) {
            h[jj]  = bf16rne(xg[jj]);
            lo[jj] = bf16rne(xg[jj] - bf16tof(h[jj]));
        }
        uint2 ph, pl;
        ph.x = (unsigned)h[0]  | ((unsigned)h[1]  << 16);
        ph.y = (unsigned)h[2]  | ((unsigned)h[3]  << 16);
        pl.x = (unsigned)lo[0] | ((unsigned)lo[1] << 16);
        pl.y = (unsigned)lo[2] | ((unsigned)lo[3] << 16);
        *reinterpret_cast<uint2*>(&xtf[st_off])        = ph;
        *reinterpret_cast<uint2*>(&xtf[XTFH + st_off]) = pl;
    }
    __syncthreads();

    for (int kt = 0; kt < 16; ++kt) {
        const int cur = kt & 1;
        float xg[4];
        if (kt < 15) {
            #pragma unroll
            for (int jj = 0; jj < 4; ++jj)
                xg[jj] = xb[(size_t)((kt + 1) * 32 + g_k4 + jj) * PN + g_col];
        }
        const ushort_t* xh = xtf + cur * 2 * XTFH;
        const ushort_t* xl = xh + XTFH;
        bf16x8 bh[4], bl[4];
        #pragma unroll
        for (int n = 0; n < 4; ++n) {
            bh[n] = *reinterpret_cast<const bf16x8*>(&xh[(n * 64 + l) * 8]);
            bl[n] = *reinterpret_cast<const bf16x8*>(&xl[(n * 64 + l) * 8]);
        }
        #pragma unroll
        for (int m = 0; m < 4; ++m) {
            const int row = w * 64 + m * 16 + lr;
            const bf16x8 ah = *reinterpret_cast<const bf16x8*>(&wv_hi[(size_t)row * C + kt * 32 + lg * 8]);
            const bf16x8 al = *reinterpret_cast<const bf16x8*>(&wv_lo[(size_t)row * C + kt * 32 + lg * 8]);
            #pragma unroll
            for (int n = 0; n < 4; ++n) {
                acc[m][n] = __builtin_amdgcn_mfma_f32_16x16x32_bf16(ah, bh[n], acc[m][n], 0, 0, 0);
                acc[m][n] = __builtin_amdgcn_mfma_f32_16x16x32_bf16(ah, bl[n], acc[m][n], 0, 0, 0);
                acc[m][n] = __builtin_amdgcn_mfma_f32_16x16x32_bf16(al, bh[n], acc[m][n], 0, 0, 0);
            }
        }
        if (kt < 15) {
            ushort_t* dh = xtf + (cur ^ 1) * 2 * XTFH;
            ushort_t h[4], lo[4];
            #pragma unroll
            for (int jj = 0; jj < 4; ++jj) {
                h[jj]  = bf16rne(xg[jj]);
                lo[jj] = bf16rne(xg[jj] - bf16tof(h[jj]));
            }
            uint2 ph, pl;
            ph.x = (unsigned)h[0]  | ((unsigned)h[1]  << 16);
            ph.y = (unsigned)h[2]  | ((unsigned)h[3]  << 16);
            pl.x = (unsigned)lo[0] | ((unsigned)lo[1] << 16);
            pl.y = (unsigned)lo[2] | ((unsigned)lo[3] << 16);
            *reinterpret_cast<uint2*>(&dh[st_off])        = ph;
            *reinterpret_cast<uint2*>(&dh[XTFH + st_off]) = pl;
        }
        __syncthreads();
    }

    // finalize: global act[tb + fraglinear] = split(relu(value + b_v) * cv)
    {
        const float* bq  = b_qkv + 1 + C;
        const float* cvb = cv + bp * C;
        #pragma unroll
        for (int m = 0; m < 4; ++m) {
            const int rbase = w * 64 + m * 16 + lg * 4;
            const int ktp = w * 2 + (m >> 1);
            const int lgp = (m * 2 + (lg >> 1)) & 3;
            const int j0p = (lg & 1) * 4;
            float bias[4], cvv[4];
            #pragma unroll
            for (int j = 0; j < 4; ++j) { bias[j] = bq[rbase + j]; cvv[j] = cvb[rbase + j]; }
            #pragma unroll
            for (int n = 0; n < 4; ++n) {
                ushort_t hh[4], ll[4];
                #pragma unroll
                for (int j = 0; j < 4; ++j) {
                    const float av = fmaxf(acc[m][n][j] + bias[j], 0.f) * cvv[j];
                    hh[j] = bf16rne(av);
                    ll[j] = bf16rne(av - bf16tof(hh[j]));
                }
                uint2 ph, pl;
                ph.x = (unsigned)hh[0] | ((unsigned)hh[1] << 16);
                ph.y = (unsigned)hh[2] | ((unsigned)hh[3] << 16);
                pl.x = (unsigned)ll[0] | ((unsigned)ll[1] << 16);
                pl.y = (unsigned)ll[2] | ((unsigned)ll[3] << 16);
                const size_t off = tb + ((ktp * 4 + n) * 64 + lgp * 16 + lr) * 8 + j0p;
                *reinterpret_cast<uint2*>(&act_hi[off]) = ph;
                *reinterpret_cast<uint2*>(&act_lo[off]) = pl;
            }
        }
    }
}

// ---------------------------------------------------------------------------
// Kernel 5b (split path): k_out — out = Wo @ act + b_out.
// act read frag-linear straight from global (1 KB/wave coalesced loads).
// ZERO LDS, ZERO barriers -> ~3 blocks/CU, waves free-run.
// ---------------------------------------------------------------------------
__global__ __launch_bounds__(512) void k_out(
    const ushort_t* __restrict__ act_hi, const ushort_t* __restrict__ act_lo,
    const ushort_t* __restrict__ wo_hi, const ushort_t* __restrict__ wo_lo,
    const float* __restrict__ b_out, float* __restrict__ out) {

    const int nt = blockIdx.x, bp = blockIdx.y;
    const int b = bp >> 2, p = bp & 3;
    const int n0 = nt * 64;
    const int tid = threadIdx.x;
    const int w  = tid >> 6;
    const int l  = tid & 63;
    const int lr = l & 15;
    const int lg = l >> 4;
    const size_t tb = (size_t)(bp * 16 + nt) * TILE_SH;

    f32x4 acc2[4][4];
    #pragma unroll
    for (int m = 0; m < 4; ++m)
        #pragma unroll
        for (int n = 0; n < 4; ++n) acc2[m][n] = (f32x4){0.f, 0.f, 0.f, 0.f};

    for (int kt = 0; kt < 16; ++kt) {
        bf16x8 bh[4], bl[4];
        #pragma unroll
        for (int n = 0; n < 4; ++n) {
            bh[n] = *reinterpret_cast<const bf16x8*>(&act_hi[tb + ((kt * 4 + n) * 64 + l) * 8]);
            bl[n] = *reinterpret_cast<const bf16x8*>(&act_lo[tb + ((kt * 4 + n) * 64 + l) * 8]);
        }
        #pragma unroll
        for (int m = 0; m < 4; ++m) {
            const int row = w * 64 + m * 16 + lr;
            const bf16x8 ah = *reinterpret_cast<const bf16x8*>(&wo_hi[(size_t)row * C + kt * 32 + lg * 8]);
            const bf16x8 al = *reinterpret_cast<const bf16x8*>(&wo_lo[(size_t)row * C + kt * 32 + lg * 8]);
            #pragma unroll
            for (int n = 0; n < 4; ++n) {
                acc2[m][n] = __builtin_amdgcn_mfma_f32_16x16x32_bf16(ah, bh[n], acc2[m][n], 0, 0, 0);
                acc2[m][n] = __builtin_amdgcn_mfma_f32_16x16x32_bf16(ah, bl[n], acc2[m][n], 0, 0, 0);
                acc2[m][n] = __builtin_amdgcn_mfma_f32_16x16x32_bf16(al, bh[n], acc2[m][n], 0, 0, 0);
            }
        }
    }

    #pragma unroll
    for (int m = 0; m < 4; ++m) {
        #pragma unroll
        for (int j = 0; j < 4; ++j) {
            const int row = w * 64 + m * 16 + lg * 4 + j;
            const float bo = b_out[row];
            float* orow = out + ((size_t)(b * C + row) * P + p) * NN + n0;
            #pragma unroll
            for (int n = 0; n < 4; ++n)
                orow[n * 16 + lr] = acc2[m][n][j] + bo;
        }
    }
}

// ---------------------------------------------------------------------------
// Kernel 5 (fallback, fused): identical to R4 k_vo. Used only if ws too small.
// ---------------------------------------------------------------------------
__global__ __launch_bounds__(512, 1) void k_vo_fused(
    const float* __restrict__ x,
    const ushort_t* __restrict__ wv_hi, const ushort_t* __restrict__ wv_lo,
    const ushort_t* __restrict__ wo_hi, const ushort_t* __restrict__ wo_lo,
    const float* __restrict__ b_qkv, const float* __restrict__ b_out,
    const float* __restrict__ cv, float* __restrict__ out) {

    extern __shared__ char lds_raw[];
    ushort_t* actf_hi = (ushort_t*)lds_raw;
    ushort_t* actf_lo = actf_hi + 16 * 4 * 64 * 8;
    ushort_t* xtf     = actf_lo + 16 * 4 * 64 * 8;

    const int nt = blockIdx.x, bp = blockIdx.y;
    const int b = bp >> 2, p = bp & 3;
    const int n0 = nt * 64;
    const int tid = threadIdx.x;
    const int w  = tid >> 6;
    const int l  = tid & 63;
    const int lr = l & 15;
    const int lg = l >> 4;

    const float* xb = x + (size_t)b * C * PN + (size_t)p * NN + n0;

    const int g_col = tid & 63;
    const int g_k4  = (tid >> 6) * 4;
    const int st_off = (((g_col >> 4) * 64 + (g_k4 >> 3) * 16 + (g_col & 15)) * 8) + (g_k4 & 7);

    f32x4 acc[4][4];
    #pragma unroll
    for (int m = 0; m < 4; ++m)
        #pragma unroll
        for (int n = 0; n < 4; ++n) acc[m][n] = (f32x4){0.f, 0.f, 0.f, 0.f};

    {
        float xg[4];
        #pragma unroll
        for (int jj = 0; jj < 4; ++jj) xg[jj] = xb[(size_t)(g_k4 + jj) * PN + g_col];
        ushort_t h[4], lo[4];
        #pragma unroll
        for (int jj = 0; jj < 4; ++jj) {
            h[jj]  = bf16rne(xg[jj]);
            lo[jj] = bf16rne(xg[jj] - bf16tof(h[jj]));
        }
        uint2 ph, pl;
        ph.x = (unsigned)h[0]  | ((unsigned)h[1]  << 16);
        ph.y = (unsigned)h[2]  | ((unsigned)h[3]  << 16);
        pl.x = (unsigned)lo[0] | ((unsigned)lo[1] << 16);
        pl.y = (unsigned)lo[2] | ((unsigned)lo[3] << 16);
        *reinterpret_cast<uint2*>(&xtf[st_off])        = ph;
        *reinterpret_cast<uint2*>(&xtf[XTFH + st_off]) = pl;
    }
    __syncthreads();

    for (int kt = 0; kt < 16; ++kt) {
        const int cur = kt & 1;
        float xg[4];
        if (kt < 15) {
            #pragma unroll
            for (int jj = 0; jj < 4; ++jj)
                xg[jj] = xb[(size_t)((kt + 1) * 32 + g_k4 + jj) * PN + g_col];
        }
        const ushort_t* xh = xtf + cur * 2 * XTFH;
        const ushort_t* xl = xh + XTFH;
        bf16x8 bh[4], bl[4];
        #pragma unroll
        for (int n = 0; n < 4; ++n) {
            bh[n] = *reinterpret_cast<const bf16x8*>(&xh[(n * 64 + l) * 8]);
            bl[n] = *reinterpret_cast<const bf16x8*>(&xl[(n * 64 + l) * 8]);
        }
        #pragma unroll
        for (int m = 0; m < 4; ++m) {
            const int row = w * 64 + m * 16 + lr;
            const bf16x8 ah = *reinterpret_cast<const bf16x8*>(&wv_hi[(size_t)row * C + kt * 32 + lg * 8]);
            const bf16x8 al = *reinterpret_cast<const bf16x8*>(&wv_lo[(size_t)row * C + kt * 32 + lg * 8]);
            #pragma unroll
            for (int n = 0; n < 4; ++n) {
                acc[m][n] = __builtin_amdgcn_mfma_f32_16x16x32_bf16(ah, bh[n], acc[m][n], 0, 0, 0);
                acc[m][n] = __builtin_amdgcn_mfma_f32_16x16x32_bf16(ah, bl[n], acc[m][n], 0, 0, 0);
                acc[m][n] = __builtin_amdgcn_mfma_f32_16x16x32_bf16(al, bh[n], acc[m][n], 0, 0, 0);
            }
        }
        if (kt < 15) {
            ushort_t* dh = xtf + (cur ^ 1) * 2 * XTFH;
            ushort_t h[4], lo[4];
            #pragma unroll
            for (int jj = 0; jj < 4; ++jj) {
                h[jj]  = bf16rne(xg[jj]);
                lo[jj] = bf16rne(xg[jj] - bf16tof(h[jj]));
            }
            uint2 ph, pl;
            ph.x = (unsigned)h[0]  | ((unsigned)h[1]  << 16);
            ph.y = (unsigned)h[2]  | ((unsigned)h[3]  << 16);
            pl.x = (unsigned)lo[0] | ((unsigned)lo[1] << 16);
            pl.y = (unsigned)lo[2] | ((unsigned)lo[3] << 16);
            *reinterpret_cast<uint2*>(&dh[st_off])        = ph;
            *reinterpret_cast<uint2*>(&dh[XTFH + st_off]) = pl;
        }
        __syncthreads();
    }

    {
        const float* bq  = b_qkv + 1 + C;
        const float* cvb = cv + bp * C;
        #pragma unroll
        for (int m = 0; m < 4; ++m) {
            const int rbase = w * 64 + m * 16 + lg * 4;
            const int ktp = w * 2 + (m >> 1);
            const int lgp = (m * 2 + (lg >> 1)) & 3;
            const int j0p = (lg & 1) * 4;
            float bias[4], cvv[4];
            #pragma unroll
            for (int j = 0; j < 4; ++j) { bias[j] = bq[rbase + j]; cvv[j] = cvb[rbase + j]; }
            #pragma unroll
            for (int n = 0; n < 4; ++n) {
                ushort_t hh[4], ll[4];
                #pragma unroll
                for (int j = 0; j < 4; ++j) {
                    const float av = fmaxf(acc[m][n][j] + bias[j], 0.f) * cvv[j];
                    hh[j] = bf16rne(av);
                    ll[j] = bf16rne(av - bf16tof(hh[j]));
                }
                uint2 ph, pl;
                ph.x = (unsigned)hh[0] | ((unsigned)hh[1] << 16);
                ph.y = (unsigned)hh[2] | ((unsigned)hh[3] << 16);
                pl.x = (unsigned)ll[0] | ((unsigned)ll[1] << 16);
                pl.y = (unsigned)ll[2] | ((unsigned)ll[3] << 16);
                const int off = ((ktp * 4 + n) * 64 + lgp * 16 + lr) * 8 + j0p;
                *reinterpret_cast<uint2*>(&actf_hi[off]) = ph;
                *reinterpret_cast<uint2*>(&actf_lo[off]) = pl;
            }
        }
    }
    __syncthreads();

    f32x4 acc2[4][4];
    #pragma unroll
    for (int m = 0; m < 4; ++m)
        #pragma unroll
        for (int n = 0; n < 4; ++n) acc2[m][n] = (f32x4){0.f, 0.f, 0.f, 0.f};

    for (int kt = 0; kt < 16; ++kt) {
        bf16x8 bh[4], bl[4];
        #pragma unroll
        for (int n = 0; n < 4; ++n) {
            bh[n] = *reinterpret_cast<const bf16x8*>(&actf_hi[((kt * 4 + n) * 64 + l) * 8]);
            bl[n] = *reinterpret_cast<const bf16x8*>(&actf_lo[((kt * 4 + n) * 64 + l) * 8]);
        }
        #pragma unroll
        for (int m = 0; m < 4; ++m) {
            const int row = w * 64 + m * 16 + lr;
            const bf16x8 ah = *reinterpret_cast<const bf16x8*>(&wo_hi[(size_t)row * C + kt * 32 + lg * 8]);
            const bf16x8 al = *reinterpret_cast<const bf16x8*>(&wo_lo[(size_t)row * C + kt * 32 + lg * 8]);
            #pragma unroll
            for (int n = 0; n < 4; ++n) {
                acc2[m][n] = __builtin_amdgcn_mfma_f32_16x16x32_bf16(ah, bh[n], acc2[m][n], 0, 0, 0);
                acc2[m][n] = __builtin_amdgcn_mfma_f32_16x16x32_bf16(ah, bl[n], acc2[m][n], 0, 0, 0);
                acc2[m][n] = __builtin_amdgcn_mfma_f32_16x16x32_bf16(al, bh[n], acc2[m][n], 0, 0, 0);
            }
        }
    }

    #pragma unroll
    for (int m = 0; m < 4; ++m) {
        #pragma unroll
        for (int j = 0; j < 4; ++j) {
            const int row = w * 64 + m * 16 + lg * 4 + j;
            const float bo = b_out[row];
            float* orow = out + ((size_t)(b * C + row) * P + p) * NN + n0;
            #pragma unroll
            for (int n = 0; n < 4; ++n)
                orow[n * 16 + lr] = acc2[m][n][j] + bo;
        }
    }
}

// ---------------------------------------------------------------------------
extern "C" void kernel_launch(void* const* d_in, const int* in_sizes, int n_in,
                              void* d_out, int out_size, void* d_ws, size_t ws_size,
                              hipStream_t stream) {
    const float* x     = (const float*)d_in[0];
    const float* w_qkv = (const float*)d_in[1];
    const float* b_qkv = (const float*)d_in[2];
    const float* w_out = (const float*)d_in[3];
    const float* b_out = (const float*)d_in[4];
    float* out = (float*)d_out;

    float* qpart  = (float*)d_ws;                    // 8*BP*NN   (2 MB)
    float* scores = qpart + 8 * BP * NN;             // BP*NN
    float* xs     = scores + BP * NN;                // BP*C
    float* cv     = xs + BP * C;                     // BP*C
    ushort_t* wsp = (ushort_t*)(cv + BP * C);
    ushort_t* wv_hi = wsp;                           // each C*C bf16 (512 KB)
    ushort_t* wv_lo = wsp + C * C;
    ushort_t* wo_hi = wsp + 2 * C * C;
    ushort_t* wo_lo = wsp + 3 * C * C;
    ushort_t* act_hi = wsp + 4 * (size_t)C * C;      // NTILES*TILE_SH (64 MB)
    ushort_t* act_lo = act_hi + (size_t)NTILES * TILE_SH;
    const size_t need = (size_t)((char*)(act_lo + (size_t)NTILES * TILE_SH) - (char*)d_ws);

    k_split  <<<dim3(512),     256, 0, stream>>>(w_qkv, w_out, wv_hi, wv_lo, wo_hi, wo_lo);
    k_query  <<<dim3(BP * 8),  256, 0, stream>>>(x, w_qkv, (float4*)qpart);
    k_softmax<<<dim3(BP),      256, 0, stream>>>((const float4*)qpart, (float4*)scores);
    k_xs     <<<dim3(BP * 16), 256, 0, stream>>>(x, (const float4*)scores, xs);
    k_cv     <<<dim3(BP),      256, 0, stream>>>(xs, w_qkv, b_qkv, cv);

    if (ws_size >= need) {
        k_value<<<dim3(16, BP), 512, 0, stream>>>(x, wv_hi, wv_lo, b_qkv, cv, act_hi, act_lo);
        k_out  <<<dim3(16, BP), 512, 0, stream>>>(act_hi, act_lo, wo_hi, wo_lo, b_out, out);
    } else {
        const size_t ldsbytes = (size_t)(2 * 16 * 4 * 64 * 8 + 2 * 2 * XTFH) * sizeof(ushort_t);
        k_vo_fused<<<dim3(16, BP), 512, ldsbytes, stream>>>(x, wv_hi, wv_lo, wo_hi, wo_lo,
                                                            b_qkv, b_out, cv, out);
    }
}

// Round 10
// 647.979 us; speedup vs baseline: 1.0182x; 1.0182x over previous
//
#include <hip/hip_runtime.h>
#include <math.h>

// Shapes (fixed by the problem)
#define BB 16
#define C  512
#define P  4
#define NN 1024
#define BP (BB*P)     // 64
#define PN (P*NN)     // 4096 floats: stride between channels c for fixed (b,p)

typedef short bf16x8 __attribute__((ext_vector_type(8)));
typedef float f32x4  __attribute__((ext_vector_type(4)));
typedef unsigned short ushort_t;

#define XTFH 2048                    // shorts per (buf,dtype): 4*64*8
#define TILE_SH 32768                // shorts per act tile (16kt*4n*64l*8j)
#define SLICE_SH 2048                // shorts per (kt, dtype) slice of act
#define NTILES 1024                  // 16 nt * 64 bp

__device__ __forceinline__ ushort_t bf16rne(float f) {
    unsigned u = __float_as_uint(f);
    u += 0x7FFFu + ((u >> 16) & 1u);
    return (ushort_t)(u >> 16);
}
__device__ __forceinline__ float bf16tof(ushort_t h) {
    return __uint_as_float(((unsigned)h) << 16);
}

// ---------------------------------------------------------------------------
// Kernel 0: split weights into bf16 hi/lo.  512 blocks x 256.
// ---------------------------------------------------------------------------
__global__ __launch_bounds__(256) void k_split(const float* __restrict__ w_qkv,
                                               const float* __restrict__ w_out,
                                               ushort_t* __restrict__ wv_hi,
                                               ushort_t* __restrict__ wv_lo,
                                               ushort_t* __restrict__ wo_hi,
                                               ushort_t* __restrict__ wo_lo) {
    const int i = blockIdx.x * 256 + threadIdx.x;   // 0..131071
    const int e = i * 4;
    const float* src; ushort_t *dh, *dl; int off;
    if (e < C * C) { src = w_qkv + (size_t)(1 + C) * C; dh = wv_hi; dl = wv_lo; off = e; }
    else           { src = w_out;                       dh = wo_hi; dl = wo_lo; off = e - C * C; }
    const float4 v = *reinterpret_cast<const float4*>(src + off);
    const float vv[4] = {v.x, v.y, v.z, v.w};
    ushort_t h[4], l[4];
    #pragma unroll
    for (int j = 0; j < 4; ++j) {
        h[j] = bf16rne(vv[j]);
        l[j] = bf16rne(vv[j] - bf16tof(h[j]));
    }
    uint2 ph, pl;
    ph.x = (unsigned)h[0] | ((unsigned)h[1] << 16);
    ph.y = (unsigned)h[2] | ((unsigned)h[3] << 16);
    pl.x = (unsigned)l[0] | ((unsigned)l[1] << 16);
    pl.y = (unsigned)l[2] | ((unsigned)l[3] << 16);
    *reinterpret_cast<uint2*>(dh + off) = ph;
    *reinterpret_cast<uint2*>(dl + off) = pl;
}

// ---------------------------------------------------------------------------
// Kernel 1: qpart[cc][bp][n] = sum_{c in chunk cc} w_q[c] * x[b,c,p,n]
// ---------------------------------------------------------------------------
__global__ __launch_bounds__(256) void k_query(const float* __restrict__ x,
                                               const float* __restrict__ w_qkv,
                                               float4* __restrict__ qpart4) {
    __shared__ float wq[64];
    const int bp = blockIdx.x >> 3, cc = blockIdx.x & 7;
    const int b = bp >> 2, p = bp & 3;
    const int tid = threadIdx.x;
    if (tid < 64) wq[tid] = w_qkv[cc * 64 + tid];
    __syncthreads();
    const float* xb = x + (size_t)b * C * PN + (size_t)p * NN;
    f32x4 acc[8];
    #pragma unroll
    for (int a = 0; a < 8; ++a) acc[a] = (f32x4){0.f, 0.f, 0.f, 0.f};
    #pragma unroll 8
    for (int i = 0; i < 64; ++i) {
        const float4 v = *reinterpret_cast<const float4*>(xb + (size_t)(cc * 64 + i) * PN + tid * 4);
        const float wv = wq[i];
        acc[i & 7][0] = fmaf(v.x, wv, acc[i & 7][0]);
        acc[i & 7][1] = fmaf(v.y, wv, acc[i & 7][1]);
        acc[i & 7][2] = fmaf(v.z, wv, acc[i & 7][2]);
        acc[i & 7][3] = fmaf(v.w, wv, acc[i & 7][3]);
    }
    f32x4 s = ((acc[0] + acc[1]) + (acc[2] + acc[3])) + ((acc[4] + acc[5]) + (acc[6] + acc[7]));
    float4 o; o.x = s[0]; o.y = s[1]; o.z = s[2]; o.w = s[3];
    qpart4[(cc * BP + bp) * 256 + tid] = o;
}

// ---------------------------------------------------------------------------
// Kernel 2: scores = softmax(sum_cc qpart) over N, per bp.  grid BP blocks.
// ---------------------------------------------------------------------------
__global__ __launch_bounds__(256) void k_softmax(const float4* __restrict__ qpart4,
                                                 float4* __restrict__ scores4) {
    __shared__ float red[256];
    const int bp = blockIdx.x, tid = threadIdx.x;
    float v[4] = {0.f, 0.f, 0.f, 0.f};
    #pragma unroll
    for (int cc = 0; cc < 8; ++cc) {
        const float4 q = qpart4[(cc * BP + bp) * 256 + tid];
        v[0] += q.x; v[1] += q.y; v[2] += q.z; v[3] += q.w;
    }
    float m = fmaxf(fmaxf(v[0], v[1]), fmaxf(v[2], v[3]));
    red[tid] = m; __syncthreads();
    for (int s = 128; s > 0; s >>= 1) {
        if (tid < s) red[tid] = fmaxf(red[tid], red[tid + s]);
        __syncthreads();
    }
    m = red[0]; __syncthreads();
    float sum = 0.f;
    #pragma unroll
    for (int j = 0; j < 4; ++j) { v[j] = expf(v[j] - m); sum += v[j]; }
    red[tid] = sum; __syncthreads();
    for (int s = 128; s > 0; s >>= 1) {
        if (tid < s) red[tid] += red[tid + s];
        __syncthreads();
    }
    const float inv = 1.0f / red[0];
    float4 o; o.x = v[0] * inv; o.y = v[1] * inv; o.z = v[2] * inv; o.w = v[3] * inv;
    scores4[bp * 256 + tid] = o;
}

// ---------------------------------------------------------------------------
// Kernel 3: xs[bp][c] = sum_n x[b,c,p,n] * scores[bp][n]
// ---------------------------------------------------------------------------
__global__ __launch_bounds__(256) void k_xs(const float* __restrict__ x,
                                            const float4* __restrict__ scores4,
                                            float* __restrict__ xs) {
    __shared__ float4 sc4[256];
    const int bp = blockIdx.x >> 4, cc = blockIdx.x & 15;
    const int b = bp >> 2, p = bp & 3;
    const int tid = threadIdx.x;
    sc4[tid] = scores4[bp * 256 + tid];
    __syncthreads();
    const int wave = tid >> 6, lane = tid & 63;
    const float* xb = x + (size_t)b * C * PN + (size_t)p * NN;
    #pragma unroll
    for (int r = 0; r < 8; ++r) {
        const int c = cc * 32 + wave * 8 + r;
        const float4* row4 = reinterpret_cast<const float4*>(xb + (size_t)c * PN);
        float a0 = 0.f, a1 = 0.f, a2 = 0.f, a3 = 0.f;
        #pragma unroll
        for (int j = 0; j < 4; ++j) {
            const float4 xv = row4[lane + 64 * j];
            const float4 sv = sc4[lane + 64 * j];
            a0 = fmaf(xv.x, sv.x, a0);
            a1 = fmaf(xv.y, sv.y, a1);
            a2 = fmaf(xv.z, sv.z, a2);
            a3 = fmaf(xv.w, sv.w, a3);
        }
        float acc = (a0 + a1) + (a2 + a3);
        #pragma unroll
        for (int off = 32; off > 0; off >>= 1) acc += __shfl_down(acc, off);
        if (lane == 0) xs[bp * C + c] = acc;
    }
}

// ---------------------------------------------------------------------------
// Kernel 4: cv[bp][o] = b_qkv[1+o] + sum_c w_key[o][c] * xs[bp][c]
// ---------------------------------------------------------------------------
__global__ __launch_bounds__(256) void k_cv(const float* __restrict__ xs,
                                            const float* __restrict__ w_qkv,
                                            const float* __restrict__ b_qkv,
                                            float* __restrict__ cv) {
    __shared__ float xsl[C];
    const int bp = blockIdx.x, tid = threadIdx.x;
    for (int i = tid; i < C; i += 256) xsl[i] = xs[bp * C + i];
    __syncthreads();
    const int wave = tid >> 6, lane = tid & 63;
    for (int o = wave; o < C; o += 4) {
        const float* wr = w_qkv + (size_t)(1 + o) * C;
        float acc = 0.f;
        #pragma unroll
        for (int j = 0; j < 8; ++j) acc = fmaf(wr[lane + 64 * j], xsl[lane + 64 * j], acc);
        #pragma unroll
        for (int off = 32; off > 0; off >>= 1) acc += __shfl_down(acc, off);
        if (lane == 0) cv[bp * C + o] = acc + b_qkv[1 + o];
    }
}

// ---------------------------------------------------------------------------
// Kernel 5a (split path): k_value — UNCHANGED from R8 (control for A/B).
// ---------------------------------------------------------------------------
__global__ __launch_bounds__(512) void k_value(
    const float* __restrict__ x,
    const ushort_t* __restrict__ wv_hi, const ushort_t* __restrict__ wv_lo,
    const float* __restrict__ b_qkv, const float* __restrict__ cv,
    ushort_t* __restrict__ act_hi, ushort_t* __restrict__ act_lo) {

    __shared__ ushort_t xtf[2 * 2 * XTFH];           // [buf][dtype][XTFH]

    const int nt = blockIdx.x, bp = blockIdx.y;
    const int b = bp >> 2, p = bp & 3;
    const int n0 = nt * 64;
    const int tid = threadIdx.x;
    const int w  = tid >> 6;
    const int l  = tid & 63;
    const int lr = l & 15;
    const int lg = l >> 4;

    const float* xb = x + (size_t)b * C * PN + (size_t)p * NN + n0;
    const size_t tb = (size_t)(bp * 16 + nt) * TILE_SH;

    const int g_col = tid & 63;
    const int g_k4  = (tid >> 6) * 4;
    const int st_off = (((g_col >> 4) * 64 + (g_k4 >> 3) * 16 + (g_col & 15)) * 8) + (g_k4 & 7);

    f32x4 acc[4][4];
    #pragma unroll
    for (int m = 0; m < 4; ++m)
        #pragma unroll
        for (int n = 0; n < 4; ++n) acc[m][n] = (f32x4){0.f, 0.f, 0.f, 0.f};

    // prologue: stage kt=0 into buffer 0
    {
        float xg[4];
        #pragma unroll
        for (int jj = 0; jj < 4; ++jj) xg[jj] = xb[(size_t)(g_k4 + jj) * PN + g_col];
        ushort_t h[4], lo[4];
        #pragma unroll
        for (int jj = 0; jj < 4; ++jj) {
            h[jj]  = bf16rne(xg[jj]);
            lo[jj] = bf16rne(xg[jj] - bf16tof(h[jj]));
        }
        uint2 ph, pl;
        ph.x = (unsigned)h[0]  | ((unsigned)h[1]  << 16);
        ph.y = (unsigned)h[2]  | ((unsigned)h[3]  << 16);
        pl.x = (unsigned)lo[0] | ((unsigned)lo[1] << 16);
        pl.y = (unsigned)lo[2] | ((unsigned)lo[3] << 16);
        *reinterpret_cast<uint2*>(&xtf[st_off])        = ph;
        *reinterpret_cast<uint2*>(&xtf[XTFH + st_off]) = pl;
    }
    __syncthreads();

    for (int kt = 0; kt < 16; ++kt) {
        const int cur = kt & 1;
        float xg[4];
        if (kt < 15) {
            #pragma unroll
            for (int jj = 0; jj < 4; ++jj)
                xg[jj] = xb[(size_t)((kt + 1) * 32 + g_k4 + jj) * PN + g_col];
        }
        const ushort_t* xh = xtf + cur * 2 * XTFH;
        const ushort_t* xl = xh + XTFH;
        bf16x8 bh[4], bl[4];
        #pragma unroll
        for (int n = 0; n < 4; ++n) {
            bh[n] = *reinterpret_cast<const bf16x8*>(&xh[(n * 64 + l) * 8]);
            bl[n] = *reinterpret_cast<const bf16x8*>(&xl[(n * 64 + l) * 8]);
        }
        #pragma unroll
        for (int m = 0; m < 4; ++m) {
            const int row = w * 64 + m * 16 + lr;
            const bf16x8 ah = *reinterpret_cast<const bf16x8*>(&wv_hi[(size_t)row * C + kt * 32 + lg * 8]);
            const bf16x8 al = *reinterpret_cast<const bf16x8*>(&wv_lo[(size_t)row * C + kt * 32 + lg * 8]);
            #pragma unroll
            for (int n = 0; n < 4; ++n) {
                acc[m][n] = __builtin_amdgcn_mfma_f32_16x16x32_bf16(ah, bh[n], acc[m][n], 0, 0, 0);
                acc[m][n] = __builtin_amdgcn_mfma_f32_16x16x32_bf16(ah, bl[n], acc[m][n], 0, 0, 0);
                acc[m][n] = __builtin_amdgcn_mfma_f32_16x16x32_bf16(al, bh[n], acc[m][n], 0, 0, 0);
            }
        }
        if (kt < 15) {
            ushort_t* dh = xtf + (cur ^ 1) * 2 * XTFH;
            ushort_t h[4], lo[4];
            #pragma unroll
            for (int jj = 0; jj < 4; ++jj) {
                h[jj]  = bf16rne(xg[jj]);
                lo[jj] = bf16rne(xg[jj] - bf16tof(h[jj]));
            }
            uint2 ph, pl;
            ph.x = (unsigned)h[0]  | ((unsigned)h[1]  << 16);
            ph.y = (unsigned)h[2]  | ((unsigned)h[3]  << 16);
            pl.x = (unsigned)lo[0] | ((unsigned)lo[1] << 16);
            pl.y = (unsigned)lo[2] | ((unsigned)lo[3] << 16);
            *reinterpret_cast<uint2*>(&dh[st_off])        = ph;
            *reinterpret_cast<uint2*>(&dh[XTFH + st_off]) = pl;
        }
        __syncthreads();
    }

    // finalize: global act[tb + fraglinear] = split(relu(value + b_v) * cv)
    {
        const float* bq  = b_qkv + 1 + C;
        const float* cvb = cv + bp * C;
        #pragma unroll
        for (int m = 0; m < 4; ++m) {
            const int rbase = w * 64 + m * 16 + lg * 4;
            const int ktp = w * 2 + (m >> 1);
            const int lgp = (m * 2 + (lg >> 1)) & 3;
            const int j0p = (lg & 1) * 4;
            float bias[4], cvv[4];
            #pragma unroll
            for (int j = 0; j < 4; ++j) { bias[j] = bq[rbase + j]; cvv[j] = cvb[rbase + j]; }
            #pragma unroll
            for (int n = 0; n < 4; ++n) {
                ushort_t hh[4], ll[4];
                #pragma unroll
                for (int j = 0; j < 4; ++j) {
                    const float av = fmaxf(acc[m][n][j] + bias[j], 0.f) * cvv[j];
                    hh[j] = bf16rne(av);
                    ll[j] = bf16rne(av - bf16tof(hh[j]));
                }
                uint2 ph, pl;
                ph.x = (unsigned)hh[0] | ((unsigned)hh[1] << 16);
                ph.y = (unsigned)hh[2] | ((unsigned)hh[3] << 16);
                pl.x = (unsigned)ll[0] | ((unsigned)ll[1] << 16);
                pl.y = (unsigned)ll[2] | ((unsigned)ll[3] << 16);
                const size_t off = tb + ((ktp * 4 + n) * 64 + lgp * 16 + lr) * 8 + j0p;
                *reinterpret_cast<uint2*>(&act_hi[off]) = ph;
                *reinterpret_cast<uint2*>(&act_lo[off]) = pl;
            }
        }
    }
}

// ---------------------------------------------------------------------------
// Kernel 5b (REWORKED): k_out — out = Wo @ act + b_out.
// R8 lesson: zero-LDS version stalled 68% (MfmaUtil 23%, VALUBusy 9%) — all
// 8 waves redundantly loaded the same act tile (8x L2/L3 traffic) and 64
// VGPRs couldn't keep loads in flight. Now: per-kt 8 KB act slice staged
// ONCE into double-buffered LDS (16 KB) by all 8 waves cooperatively;
// T14 issue-early/write-late: next slice's global load issues before the
// MFMA block, ds_write lands after; one barrier per kt. ds_read_b128 in
// canonical frag-linear order (conflict-free, m97 pattern).
// __launch_bounds__(512,4): cap 128 VGPR (acc 64 + frags 32 + stage 4 + addr).
// ---------------------------------------------------------------------------
__global__ __launch_bounds__(512, 4) void k_out(
    const ushort_t* __restrict__ act_hi, const ushort_t* __restrict__ act_lo,
    const ushort_t* __restrict__ wo_hi, const ushort_t* __restrict__ wo_lo,
    const float* __restrict__ b_out, float* __restrict__ out) {

    __shared__ ushort_t sact[2][2 * SLICE_SH];   // [buf][dtype(2) x 2048 shorts] = 16 KB

    const int nt = blockIdx.x, bp = blockIdx.y;
    const int b = bp >> 2, p = bp & 3;
    const int n0 = nt * 64;
    const int tid = threadIdx.x;
    const int w  = tid >> 6;
    const int l  = tid & 63;
    const int lr = l & 15;
    const int lg = l >> 4;
    const size_t tb = (size_t)(bp * 16 + nt) * TILE_SH;

    // staging role: wave w stages 512 shorts (1 KB) of the 8 KB kt-slice.
    // waves 0-3 -> hi segments 0-3, waves 4-7 -> lo segments 0-3.
    const int sd  = w >> 2;
    const int seg = w & 3;
    const ushort_t* gact = (sd ? act_lo : act_hi) + tb + seg * 512 + l * 8;
    const int ldst = sd * SLICE_SH + seg * 512 + l * 8;

    f32x4 acc2[4][4];
    #pragma unroll
    for (int m = 0; m < 4; ++m)
        #pragma unroll
        for (int n = 0; n < 4; ++n) acc2[m][n] = (f32x4){0.f, 0.f, 0.f, 0.f};

    // prologue: stage kt=0 slice into buf 0
    {
        const uint4 st = *reinterpret_cast<const uint4*>(gact);
        *reinterpret_cast<uint4*>(&sact[0][ldst]) = st;
    }
    __syncthreads();

    for (int kt = 0; kt < 16; ++kt) {
        const int cur = kt & 1;
        // issue next slice load EARLY (hides under ds_read + MFMA)
        uint4 stnext;
        if (kt < 15)
            stnext = *reinterpret_cast<const uint4*>(gact + (size_t)(kt + 1) * SLICE_SH);

        // act frags from LDS (broadcast to all waves), conflict-free b128
        bf16x8 bh[4], bl[4];
        #pragma unroll
        for (int n = 0; n < 4; ++n) {
            bh[n] = *reinterpret_cast<const bf16x8*>(&sact[cur][(n * 64 + l) * 8]);
            bl[n] = *reinterpret_cast<const bf16x8*>(&sact[cur][SLICE_SH + (n * 64 + l) * 8]);
        }
        #pragma unroll
        for (int m = 0; m < 4; ++m) {
            const int row = w * 64 + m * 16 + lr;
            const bf16x8 ah = *reinterpret_cast<const bf16x8*>(&wo_hi[(size_t)row * C + kt * 32 + lg * 8]);
            const bf16x8 al = *reinterpret_cast<const bf16x8*>(&wo_lo[(size_t)row * C + kt * 32 + lg * 8]);
            #pragma unroll
            for (int n = 0; n < 4; ++n) {
                acc2[m][n] = __builtin_amdgcn_mfma_f32_16x16x32_bf16(ah, bh[n], acc2[m][n], 0, 0, 0);
                acc2[m][n] = __builtin_amdgcn_mfma_f32_16x16x32_bf16(ah, bl[n], acc2[m][n], 0, 0, 0);
                acc2[m][n] = __builtin_amdgcn_mfma_f32_16x16x32_bf16(al, bh[n], acc2[m][n], 0, 0, 0);
            }
        }
        // write-late into the other buffer (its kt-1 readers finished at the
        // previous barrier; its kt+1 readers wait at the barrier below)
        if (kt < 15)
            *reinterpret_cast<uint4*>(&sact[cur ^ 1][ldst]) = stnext;
        __syncthreads();
    }

    #pragma unroll
    for (int m = 0; m < 4; ++m) {
        #pragma unroll
        for (int j = 0; j < 4; ++j) {
            const int row = w * 64 + m * 16 + lg * 4 + j;
            const float bo = b_out[row];
            float* orow = out + ((size_t)(b * C + row) * P + p) * NN + n0;
            #pragma unroll
            for (int n = 0; n < 4; ++n)
                orow[n * 16 + lr] = acc2[m][n][j] + bo;
        }
    }
}

// ---------------------------------------------------------------------------
// Kernel 5 (fallback, fused): identical to R4 k_vo. Used only if ws too small.
// ---------------------------------------------------------------------------
__global__ __launch_bounds__(512, 1) void k_vo_fused(
    const float* __restrict__ x,
    const ushort_t* __restrict__ wv_hi, const ushort_t* __restrict__ wv_lo,
    const ushort_t* __restrict__ wo_hi, const ushort_t* __restrict__ wo_lo,
    const float* __restrict__ b_qkv, const float* __restrict__ b_out,
    const float* __restrict__ cv, float* __restrict__ out) {

    extern __shared__ char lds_raw[];
    ushort_t* actf_hi = (ushort_t*)lds_raw;
    ushort_t* actf_lo = actf_hi + 16 * 4 * 64 * 8;
    ushort_t* xtf     = actf_lo + 16 * 4 * 64 * 8;

    const int nt = blockIdx.x, bp = blockIdx.y;
    const int b = bp >> 2, p = bp & 3;
    const int n0 = nt * 64;
    const int tid = threadIdx.x;
    const int w  = tid >> 6;
    const int l  = tid & 63;
    const int lr = l & 15;
    const int lg = l >> 4;

    const float* xb = x + (size_t)b * C * PN + (size_t)p * NN + n0;

    const int g_col = tid & 63;
    const int g_k4  = (tid >> 6) * 4;
    const int st_off = (((g_col >> 4) * 64 + (g_k4 >> 3) * 16 + (g_col & 15)) * 8) + (g_k4 & 7);

    f32x4 acc[4][4];
    #pragma unroll
    for (int m = 0; m < 4; ++m)
        #pragma unroll
        for (int n = 0; n < 4; ++n) acc[m][n] = (f32x4){0.f, 0.f, 0.f, 0.f};

    {
        float xg[4];
        #pragma unroll
        for (int jj = 0; jj < 4; ++jj) xg[jj] = xb[(size_t)(g_k4 + jj) * PN + g_col];
        ushort_t h[4], lo[4];
        #pragma unroll
        for (int jj = 0; jj < 4; ++jj) {
            h[jj]  = bf16rne(xg[jj]);
            lo[jj] = bf16rne(xg[jj] - bf16tof(h[jj]));
        }
        uint2 ph, pl;
        ph.x = (unsigned)h[0]  | ((unsigned)h[1]  << 16);
        ph.y = (unsigned)h[2]  | ((unsigned)h[3]  << 16);
        pl.x = (unsigned)lo[0] | ((unsigned)lo[1] << 16);
        pl.y = (unsigned)lo[2] | ((unsigned)lo[3] << 16);
        *reinterpret_cast<uint2*>(&xtf[st_off])        = ph;
        *reinterpret_cast<uint2*>(&xtf[XTFH + st_off]) = pl;
    }
    __syncthreads();

    for (int kt = 0; kt < 16; ++kt) {
        const int cur = kt & 1;
        float xg[4];
        if (kt < 15) {
            #pragma unroll
            for (int jj = 0; jj < 4; ++jj)
                xg[jj] = xb[(size_t)((kt + 1) * 32 + g_k4 + jj) * PN + g_col];
        }
        const ushort_t* xh = xtf + cur * 2 * XTFH;
        const ushort_t* xl = xh + XTFH;
        bf16x8 bh[4], bl[4];
        #pragma unroll
        for (int n = 0; n < 4; ++n) {
            bh[n] = *reinterpret_cast<const bf16x8*>(&xh[(n * 64 + l) * 8]);
            bl[n] = *reinterpret_cast<const bf16x8*>(&xl[(n * 64 + l) * 8]);
        }
        #pragma unroll
        for (int m = 0; m < 4; ++m) {
            const int row = w * 64 + m * 16 + lr;
            const bf16x8 ah = *reinterpret_cast<const bf16x8*>(&wv_hi[(size_t)row * C + kt * 32 + lg * 8]);
            const bf16x8 al = *reinterpret_cast<const bf16x8*>(&wv_lo[(size_t)row * C + kt * 32 + lg * 8]);
            #pragma unroll
            for (int n = 0; n < 4; ++n) {
                acc[m][n] = __builtin_amdgcn_mfma_f32_16x16x32_bf16(ah, bh[n], acc[m][n], 0, 0, 0);
                acc[m][n] = __builtin_amdgcn_mfma_f32_16x16x32_bf16(ah, bl[n], acc[m][n], 0, 0, 0);
                acc[m][n] = __builtin_amdgcn_mfma_f32_16x16x32_bf16(al, bh[n], acc[m][n], 0, 0, 0);
            }
        }
        if (kt < 15) {
            ushort_t* dh = xtf + (cur ^ 1) * 2 * XTFH;
            ushort_t h[4], lo[4];
            #pragma unroll
            for (int jj = 0; jj < 4; ++jj) {
                h[jj]  = bf16rne(xg[jj]);
                lo[jj] = bf16rne(xg[jj] - bf16tof(h[jj]));
            }
            uint2 ph, pl;
            ph.x = (unsigned)h[0]  | ((unsigned)h[1]  << 16);
            ph.y = (unsigned)h[2]  | ((unsigned)h[3]  << 16);
            pl.x = (unsigned)lo[0] | ((unsigned)lo[1] << 16);
            pl.y = (unsigned)lo[2] | ((unsigned)lo[3] << 16);
            *reinterpret_cast<uint2*>(&dh[st_off])        = ph;
            *reinterpret_cast<uint2*>(&dh[XTFH + st_off]) = pl;
        }
        __syncthreads();
    }

    {
        const float* bq  = b_qkv + 1 + C;
        const float* cvb = cv + bp * C;
        #pragma unroll
        for (int m = 0; m < 4; ++m) {
            const int rbase = w * 64 + m * 16 + lg * 4;
            const int ktp = w * 2 + (m >> 1);
            const int lgp = (m * 2 + (lg >> 1)) & 3;
            const int j0p = (lg & 1) * 4;
            float bias[4], cvv[4];
            #pragma unroll
            for (int j = 0; j < 4; ++j) { bias[j] = bq[rbase + j]; cvv[j] = cvb[rbase + j]; }
            #pragma unroll
            for (int n = 0; n < 4; ++n) {
                ushort_t hh[4], ll[4];
                #pragma unroll
                for (int j = 0; j < 4; ++j) {
                    const float av = fmaxf(acc[m][n][j] + bias[j], 0.f) * cvv[j];
                    hh[j] = bf16rne(av);
                    ll[j] = bf16rne(av - bf16tof(hh[j]));
                }
                uint2 ph, pl;
                ph.x = (unsigned)hh[0] | ((unsigned)hh[1] << 16);
                ph.y = (unsigned)hh[2] | ((unsigned)hh[3] << 16);
                pl.x = (unsigned)ll[0] | ((unsigned)ll[1] << 16);
                pl.y = (unsigned)ll[2] | ((unsigned)ll[3] << 16);
                const int off = ((ktp * 4 + n) * 64 + lgp * 16 + lr) * 8 + j0p;
                *reinterpret_cast<uint2*>(&actf_hi[off]) = ph;
                *reinterpret_cast<uint2*>(&actf_lo[off]) = pl;
            }
        }
    }
    __syncthreads();

    f32x4 acc2[4][4];
    #pragma unroll
    for (int m = 0; m < 4; ++m)
        #pragma unroll
        for (int n = 0; n < 4; ++n) acc2[m][n] = (f32x4){0.f, 0.f, 0.f, 0.f};

    for (int kt = 0; kt < 16; ++kt) {
        bf16x8 bh[4], bl[4];
        #pragma unroll
        for (int n = 0; n < 4; ++n) {
            bh[n] = *reinterpret_cast<const bf16x8*>(&actf_hi[((kt * 4 + n) * 64 + l) * 8]);
            bl[n] = *reinterpret_cast<const bf16x8*>(&actf_lo[((kt * 4 + n) * 64 + l) * 8]);
        }
        #pragma unroll
        for (int m = 0; m < 4; ++m) {
            const int row = w * 64 + m * 16 + lr;
            const bf16x8 ah = *reinterpret_cast<const bf16x8*>(&wo_hi[(size_t)row * C + kt * 32 + lg * 8]);
            const bf16x8 al = *reinterpret_cast<const bf16x8*>(&wo_lo[(size_t)row * C + kt * 32 + lg * 8]);
            #pragma unroll
            for (int n = 0; n < 4; ++n) {
                acc2[m][n] = __builtin_amdgcn_mfma_f32_16x16x32_bf16(ah, bh[n], acc2[m][n], 0, 0, 0);
                acc2[m][n] = __builtin_amdgcn_mfma_f32_16x16x32_bf16(ah, bl[n], acc2[m][n], 0, 0, 0);
                acc2[m][n] = __builtin_amdgcn_mfma_f32_16x16x32_bf16(al, bh[n], acc2[m][n], 0, 0, 0);
            }
        }
    }

    #pragma unroll
    for (int m = 0; m < 4; ++m) {
        #pragma unroll
        for (int j = 0; j < 4; ++j) {
            const int row = w * 64 + m * 16 + lg * 4 + j;
            const float bo = b_out[row];
            float* orow = out + ((size_t)(b * C + row) * P + p) * NN + n0;
            #pragma unroll
            for (int n = 0; n < 4; ++n)
                orow[n * 16 + lr] = acc2[m][n][j] + bo;
        }
    }
}

// ---------------------------------------------------------------------------
extern "C" void kernel_launch(void* const* d_in, const int* in_sizes, int n_in,
                              void* d_out, int out_size, void* d_ws, size_t ws_size,
                              hipStream_t stream) {
    const float* x     = (const float*)d_in[0];
    const float* w_qkv = (const float*)d_in[1];
    const float* b_qkv = (const float*)d_in[2];
    const float* w_out = (const float*)d_in[3];
    const float* b_out = (const float*)d_in[4];
    float* out = (float*)d_out;

    float* qpart  = (float*)d_ws;                    // 8*BP*NN   (2 MB)
    float* scores = qpart + 8 * BP * NN;             // BP*NN
    float* xs     = scores + BP * NN;                // BP*C
    float* cv     = xs + BP * C;                     // BP*C
    ushort_t* wsp = (ushort_t*)(cv + BP * C);
    ushort_t* wv_hi = wsp;                           // each C*C bf16 (512 KB)
    ushort_t* wv_lo = wsp + C * C;
    ushort_t* wo_hi = wsp + 2 * C * C;
    ushort_t* wo_lo = wsp + 3 * C * C;
    ushort_t* act_hi = wsp + 4 * (size_t)C * C;      // NTILES*TILE_SH (64 MB)
    ushort_t* act_lo = act_hi + (size_t)NTILES * TILE_SH;
    const size_t need = (size_t)((char*)(act_lo + (size_t)NTILES * TILE_SH) - (char*)d_ws);

    k_split  <<<dim3(512),     256, 0, stream>>>(w_qkv, w_out, wv_hi, wv_lo, wo_hi, wo_lo);
    k_query  <<<dim3(BP * 8),  256, 0, stream>>>(x, w_qkv, (float4*)qpart);
    k_softmax<<<dim3(BP),      256, 0, stream>>>((const float4*)qpart, (float4*)scores);
    k_xs     <<<dim3(BP * 16), 256, 0, stream>>>(x, (const float4*)scores, xs);
    k_cv     <<<dim3(BP),      256, 0, stream>>>(xs, w_qkv, b_qkv, cv);

    if (ws_size >= need) {
        k_value<<<dim3(16, BP), 512, 0, stream>>>(x, wv_hi, wv_lo, b_qkv, cv, act_hi, act_lo);
        k_out  <<<dim3(16, BP), 512, 0, stream>>>(act_hi, act_lo, wo_hi, wo_lo, b_out, out);
    } else {
        const size_t ldsbytes = (size_t)(2 * 16 * 4 * 64 * 8 + 2 * 2 * XTFH) * sizeof(ushort_t);
        k_vo_fused<<<dim3(16, BP), 512, ldsbytes, stream>>>(x, wv_hi, wv_lo, wo_hi, wo_lo,
                                                            b_qkv, b_out, cv, out);
    }
}